// Round 1
// baseline (6711.168 us; speedup 1.0000x reference)
//
#include <hip/hip_runtime.h>
#include <hip/hip_bf16.h>

// Problem constants
#define B_   128
#define T_   30
#define V_   10000
#define E_   512
#define H_   512
#define F_   4096
#define L_   2
#define VPAD 10112   // 79 * 128

typedef __attribute__((ext_vector_type(4))) float f32x4;
typedef __attribute__((ext_vector_type(8))) __bf16 bf16x8;
typedef __attribute__((ext_vector_type(8))) unsigned short u16x8;

__device__ __forceinline__ unsigned short f2bf(float x){
    unsigned int u = __float_as_uint(x);
    unsigned int r = (u + 0x7FFFu + ((u >> 16) & 1u)) >> 16;
    return (unsigned short)r;
}

// ---------------------------------------------------------------------------
// W_out [512][10000] f32  ->  WbT [VPAD][512] bf16 (transposed, zero-padded)
// ---------------------------------------------------------------------------
__global__ void __launch_bounds__(256) k_castWT(const float* __restrict__ W,
                                                unsigned short* __restrict__ WbT){
    __shared__ float tile[64][65];
    const int n0 = blockIdx.x * 64;   // 158 blocks over VPAD
    const int k0 = blockIdx.y * 64;   // 8 blocks over 512
    const int tid = threadIdx.x;
    for (int q = 0; q < 16; ++q){
        int idx = tid + q * 256;
        int kk = idx >> 6, nn = idx & 63;
        int n = n0 + nn;
        tile[kk][nn] = (n < V_) ? W[(size_t)(k0 + kk) * V_ + n] : 0.f;
    }
    __syncthreads();
    for (int q = 0; q < 16; ++q){
        int idx = tid + q * 256;
        int nn = idx >> 6, kk = idx & 63;
        WbT[(size_t)(n0 + nn) * 512 + k0 + kk] = f2bf(tile[kk][nn]);
    }
}

// ---------------------------------------------------------------------------
// xemb[t][b][e] = embedding[xTokens[b][t]][e]
// ---------------------------------------------------------------------------
__global__ void __launch_bounds__(256) k_embed(const int* __restrict__ tok,
                                               const float* __restrict__ emb,
                                               float* __restrict__ xemb){
    int g  = blockIdx.x * 256 + threadIdx.x;   // 491520 float4 granules
    int e4 = (g & 127) * 4;
    int b  = (g >> 7) & 127;
    int t  = g >> 14;
    int id = tok[b * T_ + t];
    const float4 v = *reinterpret_cast<const float4*>(emb + (size_t)id * E_ + e4);
    *reinterpret_cast<float4*>(xemb + ((size_t)t * B_ + b) * E_ + e4) = v;
}

// ---------------------------------------------------------------------------
// h0 partial: part[fs][b][h] = sum over F-chunk fs of vgg[b,:] * W_in[:,h]
// grid (16 btiles of 8, 8 fsplits of 512), 256 threads
// ---------------------------------------------------------------------------
__global__ void __launch_bounds__(256) k_h0p(const float* __restrict__ vgg,
                                             const float* __restrict__ Win,
                                             float* __restrict__ part){
    __shared__ float a[8][520];
    const int b0 = blockIdx.x * 8;
    const int fs = blockIdx.y;
    const int f0 = fs * 512;
    const int tid = threadIdx.x;
    for (int q = 0; q < 4; ++q){
        int idx = tid + q * 256;
        int r = idx >> 7, c4 = (idx & 127) * 4;
        *reinterpret_cast<float4*>(&a[r][c4]) =
            *reinterpret_cast<const float4*>(vgg + (size_t)(b0 + r) * F_ + f0 + c4);
    }
    __syncthreads();
    float acc[8][2];
    #pragma unroll
    for (int i = 0; i < 8; ++i){ acc[i][0] = 0.f; acc[i][1] = 0.f; }
    for (int f = 0; f < 512; f += 4){
        float w0a = Win[(size_t)(f0 + f    ) * H_ + tid];
        float w0b = Win[(size_t)(f0 + f    ) * H_ + tid + 256];
        float w1a = Win[(size_t)(f0 + f + 1) * H_ + tid];
        float w1b = Win[(size_t)(f0 + f + 1) * H_ + tid + 256];
        float w2a = Win[(size_t)(f0 + f + 2) * H_ + tid];
        float w2b = Win[(size_t)(f0 + f + 2) * H_ + tid + 256];
        float w3a = Win[(size_t)(f0 + f + 3) * H_ + tid];
        float w3b = Win[(size_t)(f0 + f + 3) * H_ + tid + 256];
        #pragma unroll
        for (int i = 0; i < 8; ++i){
            const float4 av = *reinterpret_cast<const float4*>(&a[i][f]);
            acc[i][0] += av.x * w0a + av.y * w1a + av.z * w2a + av.w * w3a;
            acc[i][1] += av.x * w0b + av.y * w1b + av.z * w2b + av.w * w3b;
        }
    }
    for (int i = 0; i < 8; ++i){
        part[((size_t)fs * B_ + b0 + i) * H_ + tid      ] = acc[i][0];
        part[((size_t)fs * B_ + b0 + i) * H_ + tid + 256] = acc[i][1];
    }
}

// reduce partials + bias + tanh -> hbuf layer0/parity0 and layer1/parity0
__global__ void __launch_bounds__(256) k_h0r(const float* __restrict__ part,
                                             const float* __restrict__ b_in,
                                             float* __restrict__ hbuf){
    int g  = blockIdx.x * 256 + threadIdx.x;   // 16384 float4
    int i4 = g * 4;
    float4 s = *reinterpret_cast<const float4*>(part + i4);
    for (int fs = 1; fs < 8; ++fs){
        const float4 p = *reinterpret_cast<const float4*>(part + (size_t)fs * 65536 + i4);
        s.x += p.x; s.y += p.y; s.z += p.z; s.w += p.w;
    }
    int h = i4 & 511;
    const float4 bi = *reinterpret_cast<const float4*>(b_in + h);
    float4 o;
    o.x = tanhf(s.x + bi.x); o.y = tanhf(s.y + bi.y);
    o.z = tanhf(s.z + bi.z); o.w = tanhf(s.w + bi.w);
    *reinterpret_cast<float4*>(hbuf + i4) = o;            // layer0 parity0
    *reinterpret_cast<float4*>(hbuf + 131072 + i4) = o;   // layer1 parity0
}

// ---------------------------------------------------------------------------
// Gates phase: for one (t, layer): outputs u, r (post-sigmoid) and
// cxp = x @ Wc[0:512] + bc (x-part of candidate pre-activation).
// Output columns: nt section 0 -> u, 1 -> r, 2 -> cxp.
// grid (4 btiles of 32, 24 ntiles of 64), 512 threads.
// ---------------------------------------------------------------------------
__global__ void __launch_bounds__(512) k_gates(const float* __restrict__ xsrc,
                                               const float* __restrict__ hsrc,
                                               const float* __restrict__ Wu,
                                               const float* __restrict__ Wr,
                                               const float* __restrict__ Wc,
                                               const float* __restrict__ bu,
                                               const float* __restrict__ br,
                                               const float* __restrict__ bc,
                                               float* __restrict__ ubuf,
                                               float* __restrict__ rbuf,
                                               float* __restrict__ cxbuf){
    __shared__ float a[32][132];
    const int bt = blockIdx.x;         // 0..3
    const int nt = blockIdx.y;         // 0..23
    const int sect = nt >> 3;          // 0:u 1:r 2:cx
    const int b0 = bt * 32;
    const int tid = threadIdx.x;
    const int nl = tid & 63;
    const int bg = tid >> 6;           // 0..7
    const int ncol = (nt & 7) * 64 + nl;
    const float* W = (sect == 0) ? Wu : (sect == 1) ? Wr : Wc;
    float acc[4] = {0.f, 0.f, 0.f, 0.f};
    const int nch = (sect == 2) ? 4 : 8;   // cx uses only x rows (k<512)
    for (int c = 0; c < nch; ++c){
        const float* src = (c < 4) ? xsrc : hsrc;
        const int kd = (c < 4) ? c * 128 : (c - 4) * 128;
        __syncthreads();
        {
            int idx = tid;
            #pragma unroll
            for (int q = 0; q < 2; ++q){
                int r = idx >> 5, c4 = (idx & 31) * 4;
                *reinterpret_cast<float4*>(&a[r][c4]) =
                    *reinterpret_cast<const float4*>(src + (size_t)(b0 + r) * 512 + kd + c4);
                idx += 512;
            }
        }
        __syncthreads();
        const int krow = c * 128;
        for (int kk = 0; kk < 128; kk += 4){
            const size_t wb = (size_t)(krow + kk) * 512 + ncol;
            const float w0 = W[wb];
            const float w1 = W[wb + 512];
            const float w2 = W[wb + 1024];
            const float w3 = W[wb + 1536];
            #pragma unroll
            for (int i = 0; i < 4; ++i){
                const float4 av = *reinterpret_cast<const float4*>(&a[bg * 4 + i][kk]);
                acc[i] += av.x * w0 + av.y * w1 + av.z * w2 + av.w * w3;
            }
        }
    }
    const float* bias = (sect == 0) ? bu : (sect == 1) ? br : bc;
    float* outp = (sect == 0) ? ubuf : (sect == 1) ? rbuf : cxbuf;
    const float bv = bias[ncol];
    #pragma unroll
    for (int i = 0; i < 4; ++i){
        const int b = b0 + bg * 4 + i;
        float v = acc[i] + bv;
        if (sect < 2) v = 1.f / (1.f + expf(-v));
        outp[(size_t)b * 512 + ncol] = v;
    }
}

// ---------------------------------------------------------------------------
// Candidate + state update: cand = tanh(cxp + (r*h_old) @ Wc[512:1024]);
// h_new = u*h_old + (1-u)*cand.  Also emits xs (bf16) for the logits GEMM
// and the final_state section of d_out at t == T-1.
// grid (8 btiles of 16, 8 ntiles of 64), 256 threads.
// ---------------------------------------------------------------------------
__global__ void __launch_bounds__(256) k_cand(const float* __restrict__ hold,
                                              const float* __restrict__ rbuf,
                                              const float* __restrict__ ubuf,
                                              const float* __restrict__ cxbuf,
                                              const float* __restrict__ Wc,
                                              float* __restrict__ hnew,
                                              unsigned short* __restrict__ xs16,
                                              float* __restrict__ fsout,
                                              int t, int j){
    __shared__ float a[16][132];
    const int b0 = blockIdx.x * 16;
    const int nt = blockIdx.y;
    const int tid = threadIdx.x;
    const int nl = tid & 63;
    const int bg = tid >> 6;           // 0..3
    const int n = nt * 64 + nl;
    float acc[4] = {0.f, 0.f, 0.f, 0.f};
    for (int c = 0; c < 4; ++c){
        const int kd = c * 128;
        __syncthreads();
        {
            int idx = tid;
            #pragma unroll
            for (int q = 0; q < 2; ++q){
                int r = idx >> 5, c4 = (idx & 31) * 4;
                const float4 rv = *reinterpret_cast<const float4*>(rbuf + (size_t)(b0 + r) * 512 + kd + c4);
                const float4 hv = *reinterpret_cast<const float4*>(hold + (size_t)(b0 + r) * 512 + kd + c4);
                float4 p;
                p.x = rv.x * hv.x; p.y = rv.y * hv.y; p.z = rv.z * hv.z; p.w = rv.w * hv.w;
                *reinterpret_cast<float4*>(&a[r][c4]) = p;
                idx += 256;
            }
        }
        __syncthreads();
        for (int kk = 0; kk < 128; kk += 4){
            const size_t wb = (size_t)(512 + kd + kk) * 512 + n;
            const float w0 = Wc[wb];
            const float w1 = Wc[wb + 512];
            const float w2 = Wc[wb + 1024];
            const float w3 = Wc[wb + 1536];
            #pragma unroll
            for (int i = 0; i < 4; ++i){
                const float4 av = *reinterpret_cast<const float4*>(&a[bg * 4 + i][kk]);
                acc[i] += av.x * w0 + av.y * w1 + av.z * w2 + av.w * w3;
            }
        }
    }
    #pragma unroll
    for (int i = 0; i < 4; ++i){
        const int b = b0 + bg * 4 + i;
        const float cand = tanhf(cxbuf[(size_t)b * 512 + n] + acc[i]);
        const float u = ubuf[(size_t)b * 512 + n];
        const float hv = hold[(size_t)b * 512 + n];
        const float h2 = u * hv + (1.f - u) * cand;
        hnew[(size_t)b * 512 + n] = h2;
        if (j == 1) xs16[((size_t)t * B_ + b) * 512 + n] = f2bf(h2);
        if (t == T_ - 1) fsout[(size_t)j * 65536 + (size_t)b * 512 + n] = h2;
    }
}

// ---------------------------------------------------------------------------
// Logits GEMM: C[m=t*128+b][v] = xs[m,:] @ W_out[:,v] + b_out[v]
// A = xs16 [3840][512] bf16, B = WbT [VPAD][512] bf16 (pre-transposed).
// Block tile [128m x 128n], 4 waves, wave tile [64x64] = 4x4 MFMA 16x16x32.
// grid (79 ntiles, 30 mtiles), 256 threads.
// ---------------------------------------------------------------------------
__global__ void __launch_bounds__(256) k_logits(const unsigned short* __restrict__ xs16,
                                                const unsigned short* __restrict__ WbT,
                                                const float* __restrict__ b_out,
                                                float* __restrict__ out){
    __shared__ unsigned short al[128 * 72];
    __shared__ unsigned short bl[128 * 72];
    const int n0 = blockIdx.x * 128;
    const int t  = blockIdx.y;
    const int m0 = t * 128;
    const int tid = threadIdx.x;
    const int lane = tid & 63;
    const int wid = tid >> 6;
    const int wm = (wid >> 1) * 64;
    const int wn = (wid & 1) * 64;
    f32x4 acc[4][4];
    #pragma unroll
    for (int i = 0; i < 4; ++i)
        #pragma unroll
        for (int jj = 0; jj < 4; ++jj)
            acc[i][jj] = (f32x4){0.f, 0.f, 0.f, 0.f};

    for (int c = 0; c < 8; ++c){            // K chunks of 64
        const int k0 = c * 64;
        __syncthreads();
        #pragma unroll
        for (int q = 0; q < 4; ++q){
            const int li = tid + q * 256;   // 0..1023
            const int row = li >> 3;
            const int seg = li & 7;
            *reinterpret_cast<u16x8*>(&al[row * 72 + seg * 8]) =
                *reinterpret_cast<const u16x8*>(xs16 + (size_t)(m0 + row) * 512 + k0 + seg * 8);
            *reinterpret_cast<u16x8*>(&bl[row * 72 + seg * 8]) =
                *reinterpret_cast<const u16x8*>(WbT + (size_t)(n0 + row) * 512 + k0 + seg * 8);
        }
        __syncthreads();
        #pragma unroll
        for (int ks = 0; ks < 2; ++ks){
            bf16x8 af[4], bfr[4];
            #pragma unroll
            for (int f = 0; f < 4; ++f){
                af[f]  = *reinterpret_cast<const bf16x8*>(
                    &al[(wm + f * 16 + (lane & 15)) * 72 + ks * 32 + (lane >> 4) * 8]);
                bfr[f] = *reinterpret_cast<const bf16x8*>(
                    &bl[(wn + f * 16 + (lane & 15)) * 72 + ks * 32 + (lane >> 4) * 8]);
            }
            #pragma unroll
            for (int fm = 0; fm < 4; ++fm)
                #pragma unroll
                for (int fn = 0; fn < 4; ++fn)
                    acc[fm][fn] = __builtin_amdgcn_mfma_f32_16x16x32_bf16(
                        af[fm], bfr[fn], acc[fm][fn], 0, 0, 0);
        }
    }
    // epilogue: D row = (lane>>4)*4 + mi, col = lane&15  [verified layout]
    #pragma unroll
    for (int fm = 0; fm < 4; ++fm){
        #pragma unroll
        for (int fn = 0; fn < 4; ++fn){
            const int v = n0 + wn + fn * 16 + (lane & 15);
            if (v < V_){
                const float bo = b_out[v];
                #pragma unroll
                for (int mi = 0; mi < 4; ++mi){
                    const int b = wm + fm * 16 + (lane >> 4) * 4 + mi;  // row within tile == batch
                    out[(size_t)b * (T_ * V_) + (size_t)t * V_ + v] = acc[fm][fn][mi] + bo;
                }
            }
        }
    }
}

// ---------------------------------------------------------------------------
extern "C" void kernel_launch(void* const* d_in, const int* in_sizes, int n_in,
                              void* d_out, int out_size, void* d_ws, size_t ws_size,
                              hipStream_t stream){
    const float* vgg  = (const float*)d_in[0];
    const int*   tok  = (const int*)  d_in[1];
    const float* emb  = (const float*)d_in[2];
    const float* Win  = (const float*)d_in[3];
    const float* bin  = (const float*)d_in[4];
    const float* Wu   = (const float*)d_in[5];
    const float* bu   = (const float*)d_in[6];
    const float* Wr   = (const float*)d_in[7];
    const float* br   = (const float*)d_in[8];
    const float* Wc   = (const float*)d_in[9];
    const float* bc   = (const float*)d_in[10];
    const float* Wout = (const float*)d_in[11];
    const float* bout = (const float*)d_in[12];
    float* out = (float*)d_out;

    float* ws    = (float*)d_ws;
    float* hbuf  = ws;                    // [2 layer][2 parity][128][512]
    float* ubuf  = ws + 262144;
    float* rbuf  = ws + 327680;
    float* cxbuf = ws + 393216;
    float* xemb  = ws + 458752;           // [30][128][512]
    float* h0p   = ws + 2424832;          // [8][128][512]
    unsigned short* xs16 = (unsigned short*)((char*)d_ws + 11796480);           // [3840][512]
    unsigned short* WbT  = (unsigned short*)((char*)d_ws + 11796480 + 3932160); // [VPAD][512]

    k_castWT<<<dim3(158, 8), dim3(256), 0, stream>>>(Wout, WbT);
    k_embed<<<dim3(1920), dim3(256), 0, stream>>>(tok, emb, xemb);
    k_h0p<<<dim3(16, 8), dim3(256), 0, stream>>>(vgg, Win, h0p);
    k_h0r<<<dim3(64), dim3(256), 0, stream>>>(h0p, bin, hbuf);

    for (int t = 0; t < T_; ++t){
        const int rp = t & 1, wp = rp ^ 1;
        for (int j = 0; j < L_; ++j){
            const float* xsrc = (j == 0) ? (xemb + (size_t)t * 65536)
                                         : (hbuf + (size_t)wp * 65536);           // layer0 new h
            const float* hold = hbuf + (size_t)j * 131072 + (size_t)rp * 65536;
            float* hnew       = hbuf + (size_t)j * 131072 + (size_t)wp * 65536;
            const float* Wuj = Wu + (size_t)j * 524288;
            const float* Wrj = Wr + (size_t)j * 524288;
            const float* Wcj = Wc + (size_t)j * 524288;
            const float* buj = bu + (size_t)j * 512;
            const float* brj = br + (size_t)j * 512;
            const float* bcj = bc + (size_t)j * 512;
            k_gates<<<dim3(4, 24), dim3(512), 0, stream>>>(
                xsrc, hold, Wuj, Wrj, Wcj, buj, brj, bcj, ubuf, rbuf, cxbuf);
            k_cand<<<dim3(8, 8), dim3(256), 0, stream>>>(
                hold, rbuf, ubuf, cxbuf, Wcj, hnew, xs16, out + 38400000, t, j);
        }
    }
    k_logits<<<dim3(79, 30), dim3(256), 0, stream>>>(xs16, WbT, bout, out);
}